// Round 4
// baseline (478.017 us; speedup 1.0000x reference)
//
#include <hip/hip_runtime.h>

#define NB 8
#define NT 256
#define NL 64
#define ND 768

typedef __attribute__((ext_vector_type(4))) float f32x4;
typedef __attribute__((ext_vector_type(8))) short bf16x8;

__device__ __forceinline__ ushort f2bf(float f) {
    union { float f; unsigned u; } x; x.f = f;
    unsigned u = x.u;
    return (ushort)((u + 0x7fffu + ((u >> 16) & 1u)) >> 16);
}

// ---------------- Kernel 1: k/v projections (fp32 tiled GEMM) ----------------
__global__ __launch_bounds__(256) void proj_kernel(
    const float* __restrict__ E, const float* __restrict__ Wk,
    const float* __restrict__ Wv, float* __restrict__ kws,
    float* __restrict__ vws)
{
    const float* W = (blockIdx.z == 0) ? Wk : Wv;
    float* O       = (blockIdx.z == 0) ? kws : vws;

    __shared__ float As[16][68];
    __shared__ float Bs[16][68];

    const int tid = threadIdx.x;
    const int m0 = blockIdx.x * 64;
    const int e0 = blockIdx.y * 64;
    const int ty = tid >> 4;
    const int tx = tid & 15;
    const int mm = tid >> 2;
    const int c4 = tid & 3;

    float acc[4][4];
    #pragma unroll
    for (int i = 0; i < 4; ++i)
        #pragma unroll
        for (int j = 0; j < 4; ++j) acc[i][j] = 0.f;

    for (int k0 = 0; k0 < ND; k0 += 16) {
        float4 a = *(const float4*)(E + (size_t)(m0 + mm) * ND + k0 + c4 * 4);
        float4 b = *(const float4*)(W + (size_t)(e0 + mm) * ND + k0 + c4 * 4);
        As[c4*4+0][mm] = a.x; As[c4*4+1][mm] = a.y;
        As[c4*4+2][mm] = a.z; As[c4*4+3][mm] = a.w;
        Bs[c4*4+0][mm] = b.x; Bs[c4*4+1][mm] = b.y;
        Bs[c4*4+2][mm] = b.z; Bs[c4*4+3][mm] = b.w;
        __syncthreads();
        #pragma unroll
        for (int kk = 0; kk < 16; ++kk) {
            float4 av = *(const float4*)&As[kk][ty * 4];
            float4 bv = *(const float4*)&Bs[kk][tx * 4];
            float a4[4] = {av.x, av.y, av.z, av.w};
            float b4[4] = {bv.x, bv.y, bv.z, bv.w};
            #pragma unroll
            for (int i = 0; i < 4; ++i)
                #pragma unroll
                for (int j = 0; j < 4; ++j) acc[i][j] += a4[i] * b4[j];
        }
        __syncthreads();
    }
    #pragma unroll
    for (int i = 0; i < 4; ++i) {
        float4 o;
        o.x = acc[i][0]; o.y = acc[i][1]; o.z = acc[i][2]; o.w = acc[i][3];
        *(float4*)(O + (size_t)(m0 + ty * 4 + i) * ND + e0 + tx * 4) = o;
    }
}

// ---------------- Kernel 2: MFMA segmented linear attention (pipelined) -----
// One workgroup (256 thr = 4 waves) per (b,t). Register-prefetch pipelines keep
// global loads in flight across barriers/MFMA.
__global__ __launch_bounds__(256, 3) void attn_kernel(
    const int* __restrict__ spk, const float* __restrict__ tok,
    const float* __restrict__ kws, const float* __restrict__ vws,
    float* __restrict__ out)
{
    __shared__ int mlist[NT];
    __shared__ int wavecnt[4];
    __shared__ ushort U[16384];     // 32KB union
    __shared__ ushort Sb[4096];     // 8KB  S (bf16, swizzled)

    ushort* Ab = U;                 // phase1 tok tile   [64][64] bf16
    ushort* Bb = U + 4096;          // phase1 v tile     [64][64] bf16
    ushort* kT = U + 8192;          // phase2 kT strip   [128][64] bf16
    float*  Eb = (float*)U;         // phase2 epilogue   [64][128] f32 (aliases all)

    const int bt  = blockIdx.x;
    const int b   = bt >> 8;
    const int t   = bt & 255;
    const int tid = threadIdx.x;

    // ---- Phase 0: same-speaker prefix list ----
    const int tgt = spk[b * NT + t];
    int my = -1;
    if (tid <= t) my = spk[b * NT + tid];
    const bool match = (tid <= t) && (my == tgt);
    unsigned long long bal = __ballot(match);
    const int lane = tid & 63, w = tid >> 6;
    if (lane == 0) wavecnt[w] = __popcll(bal);
    __syncthreads();
    int off = 0;
    #pragma unroll
    for (int ww = 0; ww < 4; ++ww) if (ww < w) off += wavecnt[ww];
    const int n = wavecnt[0] + wavecnt[1] + wavecnt[2] + wavecnt[3];
    const int before = __popcll(bal & ((1ull << lane) - 1ull));
    if (match) mlist[off + before] = tid;
    __syncthreads();

    const int fr = lane & 15;
    const int fq = lane >> 4;
    const int srow = tid >> 4;        // 0..15 staging row base
    const int sc4  = tid & 15;        // float4 col
    const int jp = (tid & 31) * 2;    // kT staging j pair
    const int dg = tid >> 5;          // kT staging dcol group (x16)

    const size_t tokbase = (size_t)bt * NL * ND;
    const float* vbase = vws + (size_t)b * NT * ND;
    const float* kbase = kws + (size_t)b * NT * ND;
    const float4 zf4 = make_float4(0.f, 0.f, 0.f, 0.f);
    const f32x4 z4 = {0.f, 0.f, 0.f, 0.f};

    for (int j0 = 0; j0 < n; j0 += 64) {
        // ---------------- Phase 1: S = tok @ v^T, K-tiles of 64 ----------------
        int glist[4];
        #pragma unroll
        for (int p = 0; p < 4; ++p) {
            const int r = j0 + srow + p * 16;
            glist[p] = (r < n) ? mlist[r] : -1;
        }
        float4 ta[4], va[4];
        #pragma unroll
        for (int p = 0; p < 4; ++p) {
            ta[p] = *(const float4*)(tok + tokbase + (size_t)(srow + p * 16) * ND + sc4 * 4);
            va[p] = (glist[p] >= 0)
                  ? *(const float4*)(vbase + (size_t)glist[p] * ND + sc4 * 4) : zf4;
        }
        f32x4 accS[4];
        #pragma unroll
        for (int jt = 0; jt < 4; ++jt) accS[jt] = z4;

        for (int kt = 0; kt < 12; ++kt) {
            __syncthreads();   // prev MFMA done reading Ab/Bb (or Eb reads done)
            #pragma unroll
            for (int p = 0; p < 4; ++p) {
                const int r = srow + p * 16;
                const int idx = (r * 64 + sc4 * 4) ^ ((r & 7) << 3);
                ushort4 th; th.x = f2bf(ta[p].x); th.y = f2bf(ta[p].y);
                th.z = f2bf(ta[p].z); th.w = f2bf(ta[p].w);
                ushort4 vh; vh.x = f2bf(va[p].x); vh.y = f2bf(va[p].y);
                vh.z = f2bf(va[p].z); vh.w = f2bf(va[p].w);
                *(ushort4*)&Ab[idx] = th;
                *(ushort4*)&Bb[idx] = vh;
            }
            if (kt < 11) {   // issue next tile's loads; stay in flight over MFMA
                const int c0 = (kt + 1) * 64 + sc4 * 4;
                #pragma unroll
                for (int p = 0; p < 4; ++p) {
                    ta[p] = *(const float4*)(tok + tokbase + (size_t)(srow + p * 16) * ND + c0);
                    va[p] = (glist[p] >= 0)
                          ? *(const float4*)(vbase + (size_t)glist[p] * ND + c0) : zf4;
                }
            }
            __syncthreads();
            const int arow = w * 16 + fr;
            #pragma unroll
            for (int ks = 0; ks < 2; ++ks) {
                bf16x8 af = *(const bf16x8*)&Ab[(arow * 64 + ks * 32 + fq * 8) ^ ((arow & 7) << 3)];
                #pragma unroll
                for (int jt = 0; jt < 4; ++jt) {
                    const int brow = jt * 16 + fr;
                    bf16x8 bv = *(const bf16x8*)&Bb[(brow * 64 + ks * 32 + fq * 8) ^ ((brow & 7) << 3)];
                    accS[jt] = __builtin_amdgcn_mfma_f32_16x16x32_bf16(af, bv, accS[jt], 0, 0, 0);
                }
            }
        }
        __syncthreads();
        // S -> Sb bf16 (C layout: col=lane&15, row=(lane>>4)*4+reg)
        #pragma unroll
        for (int jt = 0; jt < 4; ++jt) {
            #pragma unroll
            for (int i = 0; i < 4; ++i) {
                const int r = w * 16 + fq * 4 + i;
                const int c = jt * 16 + fr;
                Sb[(r * 64 + c) ^ ((r & 7) << 3)] = f2bf(accS[jt][i]);
            }
        }

        // ---------------- Phase 2: out = base + S @ K, 6 strips of 128 --------
        const int g0 = (j0 + jp     < n) ? mlist[j0 + jp]     : -1;
        const int g1 = (j0 + jp + 1 < n) ? mlist[j0 + jp + 1] : -1;
        float4 kr0[4], kr1[4];
        #pragma unroll
        for (int c4 = 0; c4 < 4; ++c4) {
            kr0[c4] = (g0 >= 0) ? *(const float4*)(kbase + (size_t)g0 * ND + dg * 16 + c4 * 4) : zf4;
            kr1[c4] = (g1 >= 0) ? *(const float4*)(kbase + (size_t)g1 * ND + dg * 16 + c4 * 4) : zf4;
        }

        for (int st = 0; st < 6; ++st) {
            __syncthreads();   // B0: Eb reads of prev strip done / phase1 done
            #pragma unroll
            for (int c4 = 0; c4 < 4; ++c4) {
                float k0a[4] = {kr0[c4].x, kr0[c4].y, kr0[c4].z, kr0[c4].w};
                float k1a[4] = {kr1[c4].x, kr1[c4].y, kr1[c4].z, kr1[c4].w};
                #pragma unroll
                for (int e = 0; e < 4; ++e) {
                    const int dc = dg * 16 + c4 * 4 + e;
                    const unsigned pack = (unsigned)f2bf(k0a[e]) | ((unsigned)f2bf(k1a[e]) << 16);
                    *(unsigned*)&kT[(dc * 64 + jp) ^ ((dc & 7) << 3)] = pack;
                }
            }
            if (st < 5) {      // prefetch next strip's k gather
                const int c0 = (st + 1) * 128 + dg * 16;
                #pragma unroll
                for (int c4 = 0; c4 < 4; ++c4) {
                    kr0[c4] = (g0 >= 0) ? *(const float4*)(kbase + (size_t)g0 * ND + c0 + c4 * 4) : zf4;
                    kr1[c4] = (g1 >= 0) ? *(const float4*)(kbase + (size_t)g1 * ND + c0 + c4 * 4) : zf4;
                }
            }
            __syncthreads();   // B1: kT visible
            f32x4 acco[8];
            #pragma unroll
            for (int ct = 0; ct < 8; ++ct) acco[ct] = z4;
            const int arow = w * 16 + fr;
            #pragma unroll
            for (int ks = 0; ks < 2; ++ks) {
                bf16x8 af = *(const bf16x8*)&Sb[(arow * 64 + ks * 32 + fq * 8) ^ ((arow & 7) << 3)];
                #pragma unroll
                for (int ct = 0; ct < 8; ++ct) {
                    const int brow = ct * 16 + fr;
                    bf16x8 bv = *(const bf16x8*)&kT[(brow * 64 + ks * 32 + fq * 8) ^ ((brow & 7) << 3)];
                    acco[ct] = __builtin_amdgcn_mfma_f32_16x16x32_bf16(af, bv, acco[ct], 0, 0, 0);
                }
            }
            __syncthreads();   // B2: all kT reads done -> Eb may clobber
            #pragma unroll
            for (int ct = 0; ct < 8; ++ct) {
                #pragma unroll
                for (int i = 0; i < 4; ++i) {
                    const int r = w * 16 + fq * 4 + i;
                    Eb[(r * 128 + ct * 16 + fr) ^ (fq << 2)] = acco[ct][i];
                }
            }
            __syncthreads();   // B3: Eb visible
            const float* bp = (j0 == 0) ? (tok + tokbase) : (const float*)(out + tokbase);
            #pragma unroll
            for (int p = 0; p < 8; ++p) {
                const int idx = tid + p * 256;          // 0..2047
                const int row = idx >> 5;               // 0..63
                const int c4v = idx & 31;               // 0..31 (float4 col)
                f32x4 ev = *(const f32x4*)&Eb[(row * 128 + c4v * 4) ^ (((row >> 2) & 3) << 2)];
                float4 bvv = *(const float4*)(bp + (size_t)row * ND + st * 128 + c4v * 4);
                float4 o;
                o.x = bvv.x + ev[0]; o.y = bvv.y + ev[1];
                o.z = bvv.z + ev[2]; o.w = bvv.w + ev[3];
                *(float4*)(out + tokbase + (size_t)row * ND + st * 128 + c4v * 4) = o;
            }
        }
    }
}

extern "C" void kernel_launch(void* const* d_in, const int* in_sizes, int n_in,
                              void* d_out, int out_size, void* d_ws, size_t ws_size,
                              hipStream_t stream) {
    const int*   spk = (const int*)d_in[1];
    const float* tok = (const float*)d_in[2];
    const float* edu = (const float*)d_in[3];
    const float* Wk  = (const float*)d_in[4];
    const float* Wv  = (const float*)d_in[5];
    float* kws = (float*)d_ws;
    float* vws = kws + (size_t)NB * NT * ND;
    float* out = (float*)d_out;

    dim3 g1(2048 / 64, ND / 64, 2);
    proj_kernel<<<g1, 256, 0, stream>>>(edu, Wk, Wv, kws, vws);
    attn_kernel<<<NB * NT, 256, 0, stream>>>(spk, tok, kws, vws, out);
}

// Round 5
// 470.173 us; speedup vs baseline: 1.0167x; 1.0167x over previous
//
#include <hip/hip_runtime.h>
#include <hip/hip_bf16.h>

#define NB 8
#define NT 256
#define NL 64
#define ND 768

typedef __attribute__((ext_vector_type(4))) float f32x4;
typedef __attribute__((ext_vector_type(8))) short bf16x8;

__device__ __forceinline__ short f2bs(float f) {
    __hip_bfloat16 h = __float2bfloat16(f);
    return *reinterpret_cast<short*>(&h);
}
__device__ __forceinline__ unsigned pack2(float a, float b) {
    return (unsigned)(ushort)f2bs(a) | ((unsigned)(ushort)f2bs(b) << 16);
}
__device__ __forceinline__ bf16x8 cvt8(float4 x, float4 y) {
    bf16x8 r;
    r[0] = f2bs(x.x); r[1] = f2bs(x.y); r[2] = f2bs(x.z); r[3] = f2bs(x.w);
    r[4] = f2bs(y.x); r[5] = f2bs(y.y); r[6] = f2bs(y.z); r[7] = f2bs(y.w);
    return r;
}

// ---------------- Kernel 1: k/v projections (fp32 tiled GEMM) ----------------
__global__ __launch_bounds__(256) void proj_kernel(
    const float* __restrict__ E, const float* __restrict__ Wk,
    const float* __restrict__ Wv, float* __restrict__ kws,
    float* __restrict__ vws)
{
    const float* W = (blockIdx.z == 0) ? Wk : Wv;
    float* O       = (blockIdx.z == 0) ? kws : vws;

    __shared__ float As[16][68];
    __shared__ float Bs[16][68];

    const int tid = threadIdx.x;
    const int m0 = blockIdx.x * 64;
    const int e0 = blockIdx.y * 64;
    const int ty = tid >> 4;
    const int tx = tid & 15;
    const int mm = tid >> 2;
    const int c4 = tid & 3;

    float acc[4][4];
    #pragma unroll
    for (int i = 0; i < 4; ++i)
        #pragma unroll
        for (int j = 0; j < 4; ++j) acc[i][j] = 0.f;

    for (int k0 = 0; k0 < ND; k0 += 16) {
        float4 a = *(const float4*)(E + (size_t)(m0 + mm) * ND + k0 + c4 * 4);
        float4 b = *(const float4*)(W + (size_t)(e0 + mm) * ND + k0 + c4 * 4);
        As[c4*4+0][mm] = a.x; As[c4*4+1][mm] = a.y;
        As[c4*4+2][mm] = a.z; As[c4*4+3][mm] = a.w;
        Bs[c4*4+0][mm] = b.x; Bs[c4*4+1][mm] = b.y;
        Bs[c4*4+2][mm] = b.z; Bs[c4*4+3][mm] = b.w;
        __syncthreads();
        #pragma unroll
        for (int kk = 0; kk < 16; ++kk) {
            float4 av = *(const float4*)&As[kk][ty * 4];
            float4 bv = *(const float4*)&Bs[kk][tx * 4];
            float a4[4] = {av.x, av.y, av.z, av.w};
            float b4[4] = {bv.x, bv.y, bv.z, bv.w};
            #pragma unroll
            for (int i = 0; i < 4; ++i)
                #pragma unroll
                for (int j = 0; j < 4; ++j) acc[i][j] += a4[i] * b4[j];
        }
        __syncthreads();
    }
    #pragma unroll
    for (int i = 0; i < 4; ++i) {
        float4 o;
        o.x = acc[i][0]; o.y = acc[i][1]; o.z = acc[i][2]; o.w = acc[i][3];
        *(float4*)(O + (size_t)(m0 + ty * 4 + i) * ND + e0 + tx * 4) = o;
    }
}

// ---------------- Kernel 2: MFMA segmented linear attention (TLP form) ------
// 4 waves/block, one block per (b,t). Phase 1 = barrier-free direct-global
// MFMA fragments. Small LDS (25KB) -> 6 blocks/CU.
__global__ __launch_bounds__(256) void attn_kernel(
    const int* __restrict__ spk, const float* __restrict__ tok,
    const float* __restrict__ kws, const float* __restrict__ vws,
    float* __restrict__ out)
{
    __shared__ int mlist[NT];
    __shared__ int wavecnt[4];
    __shared__ ushort Sb[4096];    // S bf16 [64][64], swizzled
    __shared__ ushort kT[8192];    // kT bf16 [128 dcol][64 j], swizzled

    const int bt  = blockIdx.x;
    const int b   = bt >> 8;
    const int t   = bt & 255;
    const int tid = threadIdx.x;

    // ---- Phase 0: same-speaker prefix list ----
    const int tgt = spk[b * NT + t];
    int my = -1;
    if (tid <= t) my = spk[b * NT + tid];
    const bool match = (tid <= t) && (my == tgt);
    unsigned long long bal = __ballot(match);
    const int lane = tid & 63, w = tid >> 6;
    if (lane == 0) wavecnt[w] = __popcll(bal);
    __syncthreads();
    int off = 0;
    #pragma unroll
    for (int ww = 0; ww < 4; ++ww) if (ww < w) off += wavecnt[ww];
    const int n = wavecnt[0] + wavecnt[1] + wavecnt[2] + wavecnt[3];
    const int before = __popcll(bal & ((1ull << lane) - 1ull));
    if (match) mlist[off + before] = tid;
    __syncthreads();

    const int fr = lane & 15;
    const int fq = lane >> 4;
    const int jp = (tid & 31) * 2;   // kT staging: j pair
    const int dg = tid >> 5;         // kT staging: dcol group (x16)

    const size_t tokbase = (size_t)bt * NL * ND;
    const float* vbase = vws + (size_t)b * NT * ND;
    const float* kbase = kws + (size_t)b * NT * ND;
    const float4 zf4 = make_float4(0.f, 0.f, 0.f, 0.f);
    const f32x4 z4 = {0.f, 0.f, 0.f, 0.f};

    // per-lane A row pointer (tok row w*16+fr)
    const float* tp = tok + tokbase + (size_t)(w * 16 + fr) * ND;

    for (int j0 = 0; j0 < n; j0 += 64) {
        // k-gather row ids + strip-0 prefetch (issued BEFORE phase 1; sits in regs)
        const int g0 = (j0 + jp     < n) ? mlist[j0 + jp]     : -1;
        const int g1 = (j0 + jp + 1 < n) ? mlist[j0 + jp + 1] : -1;
        float4 kr0[4], kr1[4];
        #pragma unroll
        for (int c4 = 0; c4 < 4; ++c4) {
            kr0[c4] = (g0 >= 0) ? *(const float4*)(kbase + (size_t)g0 * ND + dg * 16 + c4 * 4) : zf4;
            kr1[c4] = (g1 >= 0) ? *(const float4*)(kbase + (size_t)g1 * ND + dg * 16 + c4 * 4) : zf4;
        }

        // ---- Phase 1: S = tok @ v^T, direct-global fragments, no barriers ----
        const float* vp[4];
        #pragma unroll
        for (int jt = 0; jt < 4; ++jt) {
            const int jj = j0 + jt * 16 + fr;
            vp[jt] = vbase + (size_t)mlist[jj < n ? jj : n - 1] * ND;
            // rows >= n produce garbage S cols; phase 2 stages those kT rows
            // as zeros so they contribute nothing.
        }
        f32x4 accS[4];
        #pragma unroll
        for (int jt = 0; jt < 4; ++jt) accS[jt] = z4;

        #pragma unroll 2
        for (int ks = 0; ks < 24; ++ks) {
            const int c = ks * 32 + fq * 8;
            float4 a0 = *(const float4*)(tp + c);
            float4 a1 = *(const float4*)(tp + c + 4);
            bf16x8 af = cvt8(a0, a1);
            #pragma unroll
            for (int jt = 0; jt < 4; ++jt) {
                float4 b0 = *(const float4*)(vp[jt] + c);
                float4 b1 = *(const float4*)(vp[jt] + c + 4);
                accS[jt] = __builtin_amdgcn_mfma_f32_16x16x32_bf16(af, cvt8(b0, b1), accS[jt], 0, 0, 0);
            }
        }

        // S -> Sb bf16 (C layout: col=lane&15, row=(lane>>4)*4+reg)
        #pragma unroll
        for (int jt = 0; jt < 4; ++jt) {
            #pragma unroll
            for (int i = 0; i < 4; ++i) {
                const int r = w * 16 + fq * 4 + i;
                const int c = jt * 16 + fr;
                Sb[(r * 64 + c) ^ ((r & 7) << 3)] = f2bs(accS[jt][i]);
            }
        }

        // ---- Phase 2: out = tok + S @ K, 6 strips of 128 cols ----
        const float* bp = (j0 == 0) ? (tok + tokbase) : (const float*)(out + tokbase);
        for (int st = 0; st < 6; ++st) {
            // residual init loads (C-layout positions), issued before the barrier
            f32x4 acco[8];
            {
                const float* rb = bp + (size_t)(w * 16 + fq * 4) * ND + st * 128 + fr;
                #pragma unroll
                for (int ct = 0; ct < 8; ++ct)
                    #pragma unroll
                    for (int i = 0; i < 4; ++i)
                        acco[ct][i] = rb[(size_t)i * ND + ct * 16];
            }
            // stage kT [128][64] from prefetched regs
            #pragma unroll
            for (int c4 = 0; c4 < 4; ++c4) {
                float k0a[4] = {kr0[c4].x, kr0[c4].y, kr0[c4].z, kr0[c4].w};
                float k1a[4] = {kr1[c4].x, kr1[c4].y, kr1[c4].z, kr1[c4].w};
                #pragma unroll
                for (int e = 0; e < 4; ++e) {
                    const int dc = dg * 16 + c4 * 4 + e;
                    *(unsigned*)&kT[(dc * 64 + jp) ^ ((dc & 7) << 3)] = pack2(k0a[e], k1a[e]);
                }
            }
            if (st < 5) {   // prefetch next strip's k gather
                const int c0 = (st + 1) * 128 + dg * 16;
                #pragma unroll
                for (int c4 = 0; c4 < 4; ++c4) {
                    kr0[c4] = (g0 >= 0) ? *(const float4*)(kbase + (size_t)g0 * ND + c0 + c4 * 4) : zf4;
                    kr1[c4] = (g1 >= 0) ? *(const float4*)(kbase + (size_t)g1 * ND + c0 + c4 * 4) : zf4;
                }
            }
            __syncthreads();   // kT (and Sb on first strip) visible
            const int arow = w * 16 + fr;
            #pragma unroll
            for (int ks = 0; ks < 2; ++ks) {
                bf16x8 af = *(const bf16x8*)&Sb[(arow * 64 + ks * 32 + fq * 8) ^ ((arow & 7) << 3)];
                #pragma unroll
                for (int ct = 0; ct < 8; ++ct) {
                    const int brow = ct * 16 + fr;
                    bf16x8 bv = *(const bf16x8*)&kT[(brow * 64 + ks * 32 + fq * 8) ^ ((brow & 7) << 3)];
                    acco[ct] = __builtin_amdgcn_mfma_f32_16x16x32_bf16(af, bv, acco[ct], 0, 0, 0);
                }
            }
            // store (scalar f32; 16-lane groups cover 64B contiguous)
            {
                float* ob = out + tokbase + (size_t)(w * 16 + fq * 4) * ND + st * 128 + fr;
                #pragma unroll
                for (int ct = 0; ct < 8; ++ct)
                    #pragma unroll
                    for (int i = 0; i < 4; ++i)
                        ob[(size_t)i * ND + ct * 16] = acco[ct][i];
            }
            __syncthreads();   // kT reads done before next strip overwrites
        }
    }
}

extern "C" void kernel_launch(void* const* d_in, const int* in_sizes, int n_in,
                              void* d_out, int out_size, void* d_ws, size_t ws_size,
                              hipStream_t stream) {
    const int*   spk = (const int*)d_in[1];
    const float* tok = (const float*)d_in[2];
    const float* edu = (const float*)d_in[3];
    const float* Wk  = (const float*)d_in[4];
    const float* Wv  = (const float*)d_in[5];
    float* kws = (float*)d_ws;
    float* vws = kws + (size_t)NB * NT * ND;
    float* out = (float*)d_out;

    dim3 g1(2048 / 64, ND / 64, 2);
    proj_kernel<<<g1, 256, 0, stream>>>(edu, Wk, Wv, kws, vws);
    attn_kernel<<<NB * NT, 256, 0, stream>>>(spk, tok, kws, vws, out);
}

// Round 6
// 458.156 us; speedup vs baseline: 1.0434x; 1.0262x over previous
//
#include <hip/hip_runtime.h>
#include <hip/hip_bf16.h>

#define NB 8
#define NT 256
#define NL 64
#define ND 768

typedef __attribute__((ext_vector_type(4))) float f32x4;
typedef __attribute__((ext_vector_type(8))) short bf16x8;

__device__ __forceinline__ short f2bs(float f) {
    __hip_bfloat16 h = __float2bfloat16(f);
    return *reinterpret_cast<short*>(&h);
}
__device__ __forceinline__ unsigned pack2(float a, float b) {
    return (unsigned)(ushort)f2bs(a) | ((unsigned)(ushort)f2bs(b) << 16);
}
__device__ __forceinline__ bf16x8 cvt8(float4 x, float4 y) {
    bf16x8 r;
    r[0] = f2bs(x.x); r[1] = f2bs(x.y); r[2] = f2bs(x.z); r[3] = f2bs(x.w);
    r[4] = f2bs(y.x); r[5] = f2bs(y.y); r[6] = f2bs(y.z); r[7] = f2bs(y.w);
    return r;
}

// ---------------- Kernel 1: k/v projections (fp32 tiled GEMM) ----------------
__global__ __launch_bounds__(256) void proj_kernel(
    const float* __restrict__ E, const float* __restrict__ Wk,
    const float* __restrict__ Wv, float* __restrict__ kws,
    float* __restrict__ vws)
{
    const float* W = (blockIdx.z == 0) ? Wk : Wv;
    float* O       = (blockIdx.z == 0) ? kws : vws;

    __shared__ float As[16][68];
    __shared__ float Bs[16][68];

    const int tid = threadIdx.x;
    const int m0 = blockIdx.x * 64;
    const int e0 = blockIdx.y * 64;
    const int ty = tid >> 4;
    const int tx = tid & 15;
    const int mm = tid >> 2;
    const int c4 = tid & 3;

    float acc[4][4];
    #pragma unroll
    for (int i = 0; i < 4; ++i)
        #pragma unroll
        for (int j = 0; j < 4; ++j) acc[i][j] = 0.f;

    for (int k0 = 0; k0 < ND; k0 += 16) {
        float4 a = *(const float4*)(E + (size_t)(m0 + mm) * ND + k0 + c4 * 4);
        float4 b = *(const float4*)(W + (size_t)(e0 + mm) * ND + k0 + c4 * 4);
        As[c4*4+0][mm] = a.x; As[c4*4+1][mm] = a.y;
        As[c4*4+2][mm] = a.z; As[c4*4+3][mm] = a.w;
        Bs[c4*4+0][mm] = b.x; Bs[c4*4+1][mm] = b.y;
        Bs[c4*4+2][mm] = b.z; Bs[c4*4+3][mm] = b.w;
        __syncthreads();
        #pragma unroll
        for (int kk = 0; kk < 16; ++kk) {
            float4 av = *(const float4*)&As[kk][ty * 4];
            float4 bv = *(const float4*)&Bs[kk][tx * 4];
            float a4[4] = {av.x, av.y, av.z, av.w};
            float b4[4] = {bv.x, bv.y, bv.z, bv.w};
            #pragma unroll
            for (int i = 0; i < 4; ++i)
                #pragma unroll
                for (int j = 0; j < 4; ++j) acc[i][j] += a4[i] * b4[j];
        }
        __syncthreads();
    }
    #pragma unroll
    for (int i = 0; i < 4; ++i) {
        float4 o;
        o.x = acc[i][0]; o.y = acc[i][1]; o.z = acc[i][2]; o.w = acc[i][3];
        *(float4*)(O + (size_t)(m0 + ty * 4 + i) * ND + e0 + tx * 4) = o;
    }
}

// ---------------- Kernel 2a: S = tok @ v^T per (b,t), bf16 S to workspace ---
// Register-double-buffered direct-global fragments, no staging barriers.
__global__ __launch_bounds__(256, 3) void s_kernel(
    const int* __restrict__ spk, const float* __restrict__ tok,
    const float* __restrict__ vws, ushort* __restrict__ S_ws, int cap)
{
    __shared__ int mlist[NT];
    __shared__ int wavecnt[4];
    __shared__ ushort Sb[4096];

    const int bt  = blockIdx.x;
    const int b   = bt >> 8;
    const int t   = bt & 255;
    const int tid = threadIdx.x;

    const int tgt = spk[b * NT + t];
    int my = -1;
    if (tid <= t) my = spk[b * NT + tid];
    const bool match = (tid <= t) && (my == tgt);
    unsigned long long bal = __ballot(match);
    const int lane = tid & 63, w = tid >> 6;
    if (lane == 0) wavecnt[w] = __popcll(bal);
    __syncthreads();
    int off = 0;
    #pragma unroll
    for (int ww = 0; ww < 4; ++ww) if (ww < w) off += wavecnt[ww];
    const int n = wavecnt[0] + wavecnt[1] + wavecnt[2] + wavecnt[3];
    const int before = __popcll(bal & ((1ull << lane) - 1ull));
    if (match) mlist[off + before] = tid;
    __syncthreads();

    const int fr = lane & 15;
    const int fq = lane >> 4;
    const size_t tokbase = (size_t)bt * NL * ND;
    const float* vbase = vws + (size_t)b * NT * ND;
    const float* tp = tok + tokbase + (size_t)(w * 16 + fr) * ND;
    const f32x4 z4 = {0.f, 0.f, 0.f, 0.f};

    const int nchunk = min((n + 63) >> 6, cap);
    for (int cc = 0; cc < nchunk; ++cc) {
        const int j0 = cc * 64;
        const float* vp[4];
        #pragma unroll
        for (int jt = 0; jt < 4; ++jt) {
            const int jj = j0 + jt * 16 + fr;
            vp[jt] = vbase + (size_t)mlist[jj < n ? jj : n - 1] * ND;
        }
        f32x4 accS[4];
        #pragma unroll
        for (int jt = 0; jt < 4; ++jt) accS[jt] = z4;

        float4 A0a, A1a, B0a[4], B1a[4], A0b, A1b, B0b[4], B1b[4];
        {
            const int c = fq * 8;
            A0a = *(const float4*)(tp + c); A1a = *(const float4*)(tp + c + 4);
            #pragma unroll
            for (int jt = 0; jt < 4; ++jt) {
                B0a[jt] = *(const float4*)(vp[jt] + c);
                B1a[jt] = *(const float4*)(vp[jt] + c + 4);
            }
        }
        #pragma unroll
        for (int ks = 0; ks < 24; ks += 2) {
            {   // issue set-b loads (iteration ks+1) before computing set-a
                const int c = (ks + 1) * 32 + fq * 8;
                A0b = *(const float4*)(tp + c); A1b = *(const float4*)(tp + c + 4);
                #pragma unroll
                for (int jt = 0; jt < 4; ++jt) {
                    B0b[jt] = *(const float4*)(vp[jt] + c);
                    B1b[jt] = *(const float4*)(vp[jt] + c + 4);
                }
            }
            {
                bf16x8 af = cvt8(A0a, A1a);
                #pragma unroll
                for (int jt = 0; jt < 4; ++jt)
                    accS[jt] = __builtin_amdgcn_mfma_f32_16x16x32_bf16(af, cvt8(B0a[jt], B1a[jt]), accS[jt], 0, 0, 0);
            }
            if (ks + 2 < 24) {   // issue set-a loads (iteration ks+2)
                const int c = (ks + 2) * 32 + fq * 8;
                A0a = *(const float4*)(tp + c); A1a = *(const float4*)(tp + c + 4);
                #pragma unroll
                for (int jt = 0; jt < 4; ++jt) {
                    B0a[jt] = *(const float4*)(vp[jt] + c);
                    B1a[jt] = *(const float4*)(vp[jt] + c + 4);
                }
            }
            {
                bf16x8 af = cvt8(A0b, A1b);
                #pragma unroll
                for (int jt = 0; jt < 4; ++jt)
                    accS[jt] = __builtin_amdgcn_mfma_f32_16x16x32_bf16(af, cvt8(B0b[jt], B1b[jt]), accS[jt], 0, 0, 0);
            }
        }

        // accS -> Sb (swizzled), then coalesced float4 store to S_ws (linear)
        #pragma unroll
        for (int jt = 0; jt < 4; ++jt) {
            #pragma unroll
            for (int i = 0; i < 4; ++i) {
                const int r = w * 16 + fq * 4 + i;
                const int c = jt * 16 + fr;
                Sb[(r * 64 + c) ^ ((r & 7) << 3)] = (ushort)f2bs(accS[jt][i]);
            }
        }
        __syncthreads();
        ushort* dst = S_ws + ((size_t)bt * 4 + cc) * 4096;
        #pragma unroll
        for (int g = 0; g < 2; ++g) {
            const int wsg = g * 256 + tid;
            const int r = wsg >> 3, c8 = wsg & 7;
            *(f32x4*)&dst[(size_t)wsg * 8] = *(const f32x4*)&Sb[(r * 64 + c8 * 8) ^ ((r & 7) << 3)];
        }
        __syncthreads();
    }
}

// ---------------- Kernel 2b: out = tok + S @ K, one 128-col strip per block --
__global__ __launch_bounds__(256, 4) void b_kernel(
    const int* __restrict__ spk, const float* __restrict__ tok,
    const float* __restrict__ kws, const ushort* __restrict__ S_ws,
    float* __restrict__ out, int cap)
{
    __shared__ int mlist[NT];
    __shared__ int wavecnt[4];
    __shared__ ushort Sb[4096];    // S bf16 [64][64], swizzled
    __shared__ ushort kT[8192];    // kT bf16 [128 dcol][64 j], swizzled

    const int bt  = blockIdx.x;
    const int st  = blockIdx.y;
    const int b   = bt >> 8;
    const int t   = bt & 255;
    const int tid = threadIdx.x;

    const int tgt = spk[b * NT + t];
    int my = -1;
    if (tid <= t) my = spk[b * NT + tid];
    const bool match = (tid <= t) && (my == tgt);
    unsigned long long bal = __ballot(match);
    const int lane = tid & 63, w = tid >> 6;
    if (lane == 0) wavecnt[w] = __popcll(bal);
    __syncthreads();
    int off = 0;
    #pragma unroll
    for (int ww = 0; ww < 4; ++ww) if (ww < w) off += wavecnt[ww];
    const int n = wavecnt[0] + wavecnt[1] + wavecnt[2] + wavecnt[3];
    const int before = __popcll(bal & ((1ull << lane) - 1ull));
    if (match) mlist[off + before] = tid;
    __syncthreads();

    const int fr = lane & 15;
    const int fq = lane >> 4;
    const int jp = (tid & 31) * 2;
    const int dg = tid >> 5;
    const size_t tokbase = (size_t)bt * NL * ND;
    const float* kbase = kws + (size_t)b * NT * ND;
    const float4 zf4 = make_float4(0.f, 0.f, 0.f, 0.f);

    // residual init: acco starts as tok values at the C-layout positions
    f32x4 acco[8];
    {
        const float* rb = tok + tokbase + (size_t)(w * 16 + fq * 4) * ND + st * 128 + fr;
        #pragma unroll
        for (int ct = 0; ct < 8; ++ct)
            #pragma unroll
            for (int i = 0; i < 4; ++i)
                acco[ct][i] = rb[(size_t)i * ND + ct * 16];
    }

    const int nchunk = min((n + 63) >> 6, cap);
    for (int cc = 0; cc < nchunk; ++cc) {
        const int j0 = cc * 64;
        const int g0 = (j0 + jp     < n) ? mlist[j0 + jp]     : -1;
        const int g1 = (j0 + jp + 1 < n) ? mlist[j0 + jp + 1] : -1;
        float4 kr0[4], kr1[4];
        #pragma unroll
        for (int c4 = 0; c4 < 4; ++c4) {
            kr0[c4] = (g0 >= 0) ? *(const float4*)(kbase + (size_t)g0 * ND + st * 128 + dg * 16 + c4 * 4) : zf4;
            kr1[c4] = (g1 >= 0) ? *(const float4*)(kbase + (size_t)g1 * ND + st * 128 + dg * 16 + c4 * 4) : zf4;
        }
        const ushort* src = S_ws + ((size_t)bt * 4 + cc) * 4096;
        f32x4 sv0 = *(const f32x4*)&src[(size_t)tid * 8];
        f32x4 sv1 = *(const f32x4*)&src[(size_t)(256 + tid) * 8];

        if (cc > 0) __syncthreads();   // prior MFMA reads done before overwrite
        {
            int wsg = tid, r = wsg >> 3, c8 = wsg & 7;
            *(f32x4*)&Sb[(r * 64 + c8 * 8) ^ ((r & 7) << 3)] = sv0;
            wsg = 256 + tid; r = wsg >> 3; c8 = wsg & 7;
            *(f32x4*)&Sb[(r * 64 + c8 * 8) ^ ((r & 7) << 3)] = sv1;
        }
        #pragma unroll
        for (int c4 = 0; c4 < 4; ++c4) {
            float k0a[4] = {kr0[c4].x, kr0[c4].y, kr0[c4].z, kr0[c4].w};
            float k1a[4] = {kr1[c4].x, kr1[c4].y, kr1[c4].z, kr1[c4].w};
            #pragma unroll
            for (int e = 0; e < 4; ++e) {
                const int dc = dg * 16 + c4 * 4 + e;
                *(unsigned*)&kT[(dc * 64 + jp) ^ ((dc & 7) << 3)] = pack2(k0a[e], k1a[e]);
            }
        }
        __syncthreads();

        const int arow = w * 16 + fr;
        #pragma unroll
        for (int ks = 0; ks < 2; ++ks) {
            bf16x8 af = *(const bf16x8*)&Sb[(arow * 64 + ks * 32 + fq * 8) ^ ((arow & 7) << 3)];
            #pragma unroll
            for (int ct = 0; ct < 8; ++ct) {
                const int brow = ct * 16 + fr;
                bf16x8 bv = *(const bf16x8*)&kT[(brow * 64 + ks * 32 + fq * 8) ^ ((brow & 7) << 3)];
                acco[ct] = __builtin_amdgcn_mfma_f32_16x16x32_bf16(af, bv, acco[ct], 0, 0, 0);
            }
        }
    }

    float* ob = out + tokbase + (size_t)(w * 16 + fq * 4) * ND + st * 128 + fr;
    #pragma unroll
    for (int ct = 0; ct < 8; ++ct)
        #pragma unroll
        for (int i = 0; i < 4; ++i)
            ob[(size_t)i * ND + ct * 16] = acco[ct][i];
}

extern "C" void kernel_launch(void* const* d_in, const int* in_sizes, int n_in,
                              void* d_out, int out_size, void* d_ws, size_t ws_size,
                              hipStream_t stream) {
    const int*   spk = (const int*)d_in[1];
    const float* tok = (const float*)d_in[2];
    const float* edu = (const float*)d_in[3];
    const float* Wk  = (const float*)d_in[4];
    const float* Wv  = (const float*)d_in[5];

    const size_t kv_floats = (size_t)NB * NT * ND;
    float* kws = (float*)d_ws;
    float* vws = kws + kv_floats;
    ushort* S_ws = (ushort*)(vws + kv_floats);
    const size_t s_bytes_per_chunkset = (size_t)NB * NT * 4096ull * 2ull; // per chunk slot
    size_t avail = (ws_size > 2 * kv_floats * 4) ? (ws_size - 2 * kv_floats * 4) : 0;
    int cap = (int)(avail / s_bytes_per_chunkset);
    if (cap > 4) cap = 4;
    if (cap < 1) cap = 1;   // (should not happen; ws is large)
    float* outp = (float*)d_out;

    dim3 g1(2048 / 64, ND / 64, 2);
    proj_kernel<<<g1, 256, 0, stream>>>(edu, Wk, Wv, kws, vws);
    s_kernel<<<NB * NT, 256, 0, stream>>>(spk, tok, vws, S_ws, cap);
    b_kernel<<<dim3(NB * NT, 6), 256, 0, stream>>>(spk, tok, kws, S_ws, outp, cap);
}

// Round 7
// 358.388 us; speedup vs baseline: 1.3338x; 1.2784x over previous
//
#include <hip/hip_runtime.h>
#include <hip/hip_bf16.h>

#define NB 8
#define NT 256
#define NL 64
#define ND 768

typedef __attribute__((ext_vector_type(4))) float f32x4;
typedef __attribute__((ext_vector_type(8))) short bf16x8;

__device__ __forceinline__ short f2bs(float f) {
    __hip_bfloat16 h = __float2bfloat16(f);
    return *reinterpret_cast<short*>(&h);
}
__device__ __forceinline__ unsigned pack2(float a, float b) {
    return (unsigned)(ushort)f2bs(a) | ((unsigned)(ushort)f2bs(b) << 16);
}

// ---------------- Kernel 1: k/v projections (fp32 tiled GEMM) ----------------
__global__ __launch_bounds__(256) void proj_kernel(
    const float* __restrict__ E, const float* __restrict__ Wk,
    const float* __restrict__ Wv, float* __restrict__ kws,
    float* __restrict__ vws)
{
    const float* W = (blockIdx.z == 0) ? Wk : Wv;
    float* O       = (blockIdx.z == 0) ? kws : vws;

    __shared__ float As[16][68];
    __shared__ float Bs[16][68];

    const int tid = threadIdx.x;
    const int m0 = blockIdx.x * 64;
    const int e0 = blockIdx.y * 64;
    const int ty = tid >> 4;
    const int tx = tid & 15;
    const int mm = tid >> 2;
    const int c4 = tid & 3;

    float acc[4][4];
    #pragma unroll
    for (int i = 0; i < 4; ++i)
        #pragma unroll
        for (int j = 0; j < 4; ++j) acc[i][j] = 0.f;

    for (int k0 = 0; k0 < ND; k0 += 16) {
        float4 a = *(const float4*)(E + (size_t)(m0 + mm) * ND + k0 + c4 * 4);
        float4 b = *(const float4*)(W + (size_t)(e0 + mm) * ND + k0 + c4 * 4);
        As[c4*4+0][mm] = a.x; As[c4*4+1][mm] = a.y;
        As[c4*4+2][mm] = a.z; As[c4*4+3][mm] = a.w;
        Bs[c4*4+0][mm] = b.x; Bs[c4*4+1][mm] = b.y;
        Bs[c4*4+2][mm] = b.z; Bs[c4*4+3][mm] = b.w;
        __syncthreads();
        #pragma unroll
        for (int kk = 0; kk < 16; ++kk) {
            float4 av = *(const float4*)&As[kk][ty * 4];
            float4 bv = *(const float4*)&Bs[kk][tx * 4];
            float a4[4] = {av.x, av.y, av.z, av.w};
            float b4[4] = {bv.x, bv.y, bv.z, bv.w};
            #pragma unroll
            for (int i = 0; i < 4; ++i)
                #pragma unroll
                for (int j = 0; j < 4; ++j) acc[i][j] += a4[i] * b4[j];
        }
        __syncthreads();
    }
    #pragma unroll
    for (int i = 0; i < 4; ++i) {
        float4 o;
        o.x = acc[i][0]; o.y = acc[i][1]; o.z = acc[i][2]; o.w = acc[i][3];
        *(float4*)(O + (size_t)(m0 + ty * 4 + i) * ND + e0 + tx * 4) = o;
    }
}

// ---------------- Kernel 2a: S = tok @ v^T (coalesced staged, LDS dbuf) -----
__global__ __launch_bounds__(256, 3) void s_kernel(
    const int* __restrict__ spk, const float* __restrict__ tok,
    const float* __restrict__ vws, ushort* __restrict__ S_ws, int cap)
{
    __shared__ int mlist[NT];
    __shared__ int wavecnt[4];
    __shared__ ushort At[2][4096];   // tok slab [64 l][64 d] bf16, swizzled
    __shared__ ushort Vt[2][4096];   // v   slab [64 j][64 d] bf16, swizzled
    __shared__ ushort Sb[4096];      // S [64 l][64 j] bf16, swizzled

    const int bt  = blockIdx.x;
    const int b   = bt >> 8;
    const int t   = bt & 255;
    const int tid = threadIdx.x;

    const int tgt = spk[b * NT + t];
    int my = -1;
    if (tid <= t) my = spk[b * NT + tid];
    const bool match = (tid <= t) && (my == tgt);
    unsigned long long bal = __ballot(match);
    const int lane = tid & 63, w = tid >> 6;
    if (lane == 0) wavecnt[w] = __popcll(bal);
    __syncthreads();
    int off = 0;
    #pragma unroll
    for (int ww = 0; ww < 4; ++ww) if (ww < w) off += wavecnt[ww];
    const int n = wavecnt[0] + wavecnt[1] + wavecnt[2] + wavecnt[3];
    const int before = __popcll(bal & ((1ull << lane) - 1ull));
    if (match) mlist[off + before] = tid;
    __syncthreads();

    const int fr = lane & 15;
    const int fq = lane >> 4;
    const int rb = tid >> 4;       // staging row base (0..15)
    const int c4 = tid & 15;       // staging float4 col

    const size_t tokbase = (size_t)bt * NL * ND;
    const float* vbase = vws + (size_t)b * NT * ND;
    const f32x4 z4 = {0.f, 0.f, 0.f, 0.f};

    const int nchunk = min((n + 63) >> 6, cap);
    for (int cc = 0; cc < nchunk; ++cc) {
        const int j0 = cc * 64;
        int gr[4];
        #pragma unroll
        for (int p = 0; p < 4; ++p) {
            const int jj = j0 + rb + 16 * p;
            gr[p] = mlist[jj < n ? jj : n - 1];
        }
        // prologue loads (dt = 0)
        float4 ta[4], va[4];
        #pragma unroll
        for (int p = 0; p < 4; ++p) {
            ta[p] = *(const float4*)(tok + tokbase + (size_t)(rb + 16 * p) * ND + c4 * 4);
            va[p] = *(const float4*)(vbase + (size_t)gr[p] * ND + c4 * 4);
        }
        f32x4 accS[4];
        #pragma unroll
        for (int jt = 0; jt < 4; ++jt) accS[jt] = z4;

        for (int dt = 0; dt < 12; ++dt) {
            const int cur = dt & 1;
            #pragma unroll
            for (int p = 0; p < 4; ++p) {
                const int row = rb + 16 * p;
                const int uidx = (row * 64 + c4 * 4) ^ ((row & 7) << 3);
                uint2 tw; tw.x = pack2(ta[p].x, ta[p].y); tw.y = pack2(ta[p].z, ta[p].w);
                uint2 vw; vw.x = pack2(va[p].x, va[p].y); vw.y = pack2(va[p].z, va[p].w);
                *(uint2*)&At[cur][uidx] = tw;
                *(uint2*)&Vt[cur][uidx] = vw;
            }
            if (dt < 11) {   // issue next slab's loads; in flight across barrier+MFMA
                const int c0 = (dt + 1) * 64 + c4 * 4;
                #pragma unroll
                for (int p = 0; p < 4; ++p) {
                    ta[p] = *(const float4*)(tok + tokbase + (size_t)(rb + 16 * p) * ND + c0);
                    va[p] = *(const float4*)(vbase + (size_t)gr[p] * ND + c0);
                }
            }
            __syncthreads();
            const int arow = w * 16 + fr;
            #pragma unroll
            for (int ks = 0; ks < 2; ++ks) {
                bf16x8 af = *(const bf16x8*)&At[cur][(arow * 64 + ks * 32 + fq * 8) ^ ((arow & 7) << 3)];
                #pragma unroll
                for (int jt = 0; jt < 4; ++jt) {
                    const int brow = jt * 16 + fr;
                    bf16x8 bv = *(const bf16x8*)&Vt[cur][(brow * 64 + ks * 32 + fq * 8) ^ ((brow & 7) << 3)];
                    accS[jt] = __builtin_amdgcn_mfma_f32_16x16x32_bf16(af, bv, accS[jt], 0, 0, 0);
                }
            }
        }

        // accS -> Sb (swizzled), then coalesced dump to S_ws
        #pragma unroll
        for (int jt = 0; jt < 4; ++jt) {
            #pragma unroll
            for (int i = 0; i < 4; ++i) {
                const int r = w * 16 + fq * 4 + i;
                const int c = jt * 16 + fr;
                Sb[(r * 64 + c) ^ ((r & 7) << 3)] = (ushort)f2bs(accS[jt][i]);
            }
        }
        __syncthreads();
        ushort* dst = S_ws + ((size_t)bt * 4 + cc) * 4096;
        #pragma unroll
        for (int g = 0; g < 2; ++g) {
            const int wsg = g * 256 + tid;
            const int r = wsg >> 3, c8 = wsg & 7;
            *(f32x4*)&dst[(size_t)wsg * 8] = *(const f32x4*)&Sb[(r * 64 + c8 * 8) ^ ((r & 7) << 3)];
        }
        __syncthreads();
    }
}

// ---------------- Kernel 2b: out = tok + S @ K, one 128-col strip per block --
__global__ __launch_bounds__(256, 4) void b_kernel(
    const int* __restrict__ spk, const float* __restrict__ tok,
    const float* __restrict__ kws, const ushort* __restrict__ S_ws,
    float* __restrict__ out, int cap)
{
    __shared__ int mlist[NT];
    __shared__ int wavecnt[4];
    __shared__ ushort Sb[4096];    // S bf16 [64 l][64 j], swizzled
    __shared__ ushort kT[8192];    // kT bf16 [128 dc][64 j], swizzled

    const int bt  = blockIdx.x;
    const int st  = blockIdx.y;
    const int b   = bt >> 8;
    const int t   = bt & 255;
    const int tid = threadIdx.x;

    const int tgt = spk[b * NT + t];
    int my = -1;
    if (tid <= t) my = spk[b * NT + tid];
    const bool match = (tid <= t) && (my == tgt);
    unsigned long long bal = __ballot(match);
    const int lane = tid & 63, w = tid >> 6;
    if (lane == 0) wavecnt[w] = __popcll(bal);
    __syncthreads();
    int off = 0;
    #pragma unroll
    for (int ww = 0; ww < 4; ++ww) if (ww < w) off += wavecnt[ww];
    const int n = wavecnt[0] + wavecnt[1] + wavecnt[2] + wavecnt[3];
    const int before = __popcll(bal & ((1ull << lane) - 1ull));
    if (match) mlist[off + before] = tid;
    __syncthreads();

    const int fr = lane & 15;
    const int fq = lane >> 4;
    const int jr = tid >> 2;       // k-row owner (0..63)
    const int q  = tid & 3;        // 4 lanes per row, contiguous 64B
    const size_t tokbase = (size_t)bt * NL * ND;
    const float* kbase = kws + (size_t)b * NT * ND;
    const f32x4 zf = {0.f, 0.f, 0.f, 0.f};

    // residual init at C-layout positions (line-optimal scalar loads)
    f32x4 acco[8];
    {
        const float* rbp = tok + tokbase + (size_t)(w * 16 + fq * 4) * ND + st * 128 + fr;
        #pragma unroll
        for (int ct = 0; ct < 8; ++ct)
            #pragma unroll
            for (int i = 0; i < 4; ++i)
                acco[ct][i] = rbp[(size_t)i * ND + ct * 16];
    }

    const int nchunk = min((n + 63) >> 6, cap);
    for (int cc = 0; cc < nchunk; ++cc) {
        const int j0 = cc * 64;
        // S chunk (coalesced)
        const ushort* src = S_ws + ((size_t)bt * 4 + cc) * 4096;
        f32x4 sv0 = *(const f32x4*)&src[(size_t)tid * 8];
        f32x4 sv1 = *(const f32x4*)&src[(size_t)(256 + tid) * 8];
        // k rows, row-granular coalesced (4 lanes x 16B per row)
        const int jj = j0 + jr;
        const int g = (jj < n) ? mlist[jj] : -1;
        f32x4 kreg[8];
        #pragma unroll
        for (int p = 0; p < 8; ++p)
            kreg[p] = (g >= 0)
                ? *(const f32x4*)(kbase + (size_t)g * ND + st * 128 + (q + 4 * p) * 4)
                : zf;

        if (cc > 0) __syncthreads();   // prior MFMA reads done before overwrite
        {
            int wsg = tid, r = wsg >> 3, c8 = wsg & 7;
            *(f32x4*)&Sb[(r * 64 + c8 * 8) ^ ((r & 7) << 3)] = sv0;
            wsg = 256 + tid; r = wsg >> 3; c8 = wsg & 7;
            *(f32x4*)&Sb[(r * 64 + c8 * 8) ^ ((r & 7) << 3)] = sv1;
        }
        #pragma unroll
        for (int p = 0; p < 8; ++p) {
            #pragma unroll
            for (int e = 0; e < 4; ++e) {
                const int dc = (q + 4 * p) * 4 + e;
                kT[(dc * 64 + jr) ^ ((dc & 7) << 3)] = (ushort)f2bs(kreg[p][e]);
            }
        }
        __syncthreads();

        const int arow = w * 16 + fr;
        #pragma unroll
        for (int ks = 0; ks < 2; ++ks) {
            bf16x8 af = *(const bf16x8*)&Sb[(arow * 64 + ks * 32 + fq * 8) ^ ((arow & 7) << 3)];
            #pragma unroll
            for (int ct = 0; ct < 8; ++ct) {
                const int brow = ct * 16 + fr;
                bf16x8 bv = *(const bf16x8*)&kT[(brow * 64 + ks * 32 + fq * 8) ^ ((brow & 7) << 3)];
                acco[ct] = __builtin_amdgcn_mfma_f32_16x16x32_bf16(af, bv, acco[ct], 0, 0, 0);
            }
        }
    }

    float* ob = out + tokbase + (size_t)(w * 16 + fq * 4) * ND + st * 128 + fr;
    #pragma unroll
    for (int ct = 0; ct < 8; ++ct)
        #pragma unroll
        for (int i = 0; i < 4; ++i)
            ob[(size_t)i * ND + ct * 16] = acco[ct][i];
}

extern "C" void kernel_launch(void* const* d_in, const int* in_sizes, int n_in,
                              void* d_out, int out_size, void* d_ws, size_t ws_size,
                              hipStream_t stream) {
    const int*   spk = (const int*)d_in[1];
    const float* tok = (const float*)d_in[2];
    const float* edu = (const float*)d_in[3];
    const float* Wk  = (const float*)d_in[4];
    const float* Wv  = (const float*)d_in[5];

    const size_t kv_floats = (size_t)NB * NT * ND;
    float* kws = (float*)d_ws;
    float* vws = kws + kv_floats;
    ushort* S_ws = (ushort*)(vws + kv_floats);
    const size_t s_bytes_per_chunkset = (size_t)NB * NT * 4096ull * 2ull;
    size_t avail = (ws_size > 2 * kv_floats * 4) ? (ws_size - 2 * kv_floats * 4) : 0;
    int cap = (int)(avail / s_bytes_per_chunkset);
    if (cap > 4) cap = 4;
    if (cap < 1) cap = 1;
    float* outp = (float*)d_out;

    dim3 g1(2048 / 64, ND / 64, 2);
    proj_kernel<<<g1, 256, 0, stream>>>(edu, Wk, Wv, kws, vws);
    s_kernel<<<NB * NT, 256, 0, stream>>>(spk, tok, vws, S_ws, cap);
    b_kernel<<<dim3(NB * NT, 6), 256, 0, stream>>>(spk, tok, kws, S_ws, outp, cap);
}